// Round 2
// baseline (883.554 us; speedup 1.0000x reference)
//
#include <hip/hip_runtime.h>

typedef _Float16 half8  __attribute__((ext_vector_type(8)));
typedef _Float16 half4_t __attribute__((ext_vector_type(4)));
typedef float    f32x4  __attribute__((ext_vector_type(4)));

static constexpr int BATCH = 16;
static constexpr int NSEQ  = 2048;
static constexpr int DDIM  = 512;
static constexpr int MROWS = BATCH * NSEQ;   // 32768

// workspace layout (bytes)
static constexpr size_t WT_OFF  = 0;                                   // 1536*512*2 = 1.5MB
static constexpr size_t QKV_OFF = 2u * 1024 * 1024;                    // 3*32768*512*2 = 96MB
static constexpr size_t VT_OFF  = QKV_OFF + (size_t)3 * MROWS * DDIM * 2; // 32MB

// ---------------- K0: weight fp32 -> fp16, transposed Wt[ng][e] = W[e][n] ----
__global__ void wt_prep(const float* __restrict__ Wq, const float* __restrict__ Wk,
                        const float* __restrict__ Wv, _Float16* __restrict__ wt) {
    int idx = blockIdx.x * 256 + threadIdx.x;   // 1536*512 total
    int ng  = idx >> 9;
    int e   = idx & 511;
    const float* W = (ng < 512) ? Wq : (ng < 1024 ? Wk : Wv);
    wt[idx] = (_Float16)W[e * 512 + (ng & 511)];
}

// ---------------- K1: fused QKV projection GEMM ------------------------------
// C[32768 x 1536] = x[32768 x 512] * W[512 x 1536] + bias, output fp16.
// Tile 64x64, BK=64, 4 waves each 32x32 via 16x16x32 f16 MFMA.
__global__ __launch_bounds__(256, 2) void qkv_gemm(
        const float* __restrict__ x, const _Float16* __restrict__ wt,
        const float* __restrict__ bq, const float* __restrict__ bk,
        const float* __restrict__ bv, _Float16* __restrict__ qkv) {
    __shared__ alignas(16) char Al[64 * 128];   // [row][64 f16] swizzled
    __shared__ alignas(16) char Bl[64 * 128];   // [col][64 f16] swizzled
    const int tid  = threadIdx.x;
    const int lane = tid & 63;
    const int wid  = tid >> 6;
    const int lg = lane >> 4, lm = lane & 15;
    const int wr = wid >> 1, wc = wid & 1;
    const int m0 = blockIdx.x * 64;
    const int n0 = blockIdx.y * 64;
    const int proj = n0 >> 9;
    const float* bias = (proj == 0) ? bq : (proj == 1 ? bk : bv);

    f32x4 acc[2][2] = {};

    for (int kk = 0; kk < 512; kk += 64) {
        __syncthreads();
        // stage A: x fp32 tile [64][64] -> f16 LDS (swizzled 16B granules)
        #pragma unroll
        for (int i = 0; i < 4; ++i) {
            int c = tid + i * 256;              // 1024 float4-chunks
            int row = c >> 4, o4 = c & 15;
            float4 v = *(const float4*)(x + (size_t)(m0 + row) * 512 + kk + o4 * 4);
            half4_t h;
            h[0] = (_Float16)v.x; h[1] = (_Float16)v.y;
            h[2] = (_Float16)v.z; h[3] = (_Float16)v.w;
            *(half4_t*)(Al + row * 128 + ((o4 * 8) ^ ((row & 7) << 4))) = h;
        }
        // stage B: Wt f16 tile [64][64]
        #pragma unroll
        for (int i = 0; i < 2; ++i) {
            int c = tid + i * 256;              // 512 16B-chunks
            int row = c >> 3, o = c & 7;
            int4 v = *(const int4*)(wt + (size_t)(n0 + row) * 512 + kk + o * 8);
            *(int4*)(Bl + row * 128 + ((o * 16) ^ ((row & 7) << 4))) = v;
        }
        __syncthreads();
        #pragma unroll
        for (int es = 0; es < 2; ++es) {
            const int off = es * 64 + lg * 16;
            const int r0 = wr * 32 + lm, r1 = r0 + 16;
            const int c0 = wc * 32 + lm, c1 = c0 + 16;
            half8 a0 = *(const half8*)(Al + r0 * 128 + (off ^ ((r0 & 7) << 4)));
            half8 a1 = *(const half8*)(Al + r1 * 128 + (off ^ ((r1 & 7) << 4)));
            half8 b0 = *(const half8*)(Bl + c0 * 128 + (off ^ ((c0 & 7) << 4)));
            half8 b1 = *(const half8*)(Bl + c1 * 128 + (off ^ ((c1 & 7) << 4)));
            acc[0][0] = __builtin_amdgcn_mfma_f32_16x16x32_f16(a0, b0, acc[0][0], 0, 0, 0);
            acc[0][1] = __builtin_amdgcn_mfma_f32_16x16x32_f16(a0, b1, acc[0][1], 0, 0, 0);
            acc[1][0] = __builtin_amdgcn_mfma_f32_16x16x32_f16(a1, b0, acc[1][0], 0, 0, 0);
            acc[1][1] = __builtin_amdgcn_mfma_f32_16x16x32_f16(a1, b1, acc[1][1], 0, 0, 0);
        }
    }
    // epilogue: bias add, store f16 to qkv[proj][m][c]
    const size_t pb = (size_t)proj * MROWS * DDIM;
    #pragma unroll
    for (int i = 0; i < 2; ++i) {
        #pragma unroll
        for (int j = 0; j < 2; ++j) {
            int mg = m0 + wr * 32 + i * 16 + lg * 4;
            int c  = (n0 & 511) + wc * 32 + j * 16 + lm;
            float bb = bias[c];
            #pragma unroll
            for (int r = 0; r < 4; ++r)
                qkv[pb + (size_t)(mg + r) * DDIM + c] = (_Float16)(acc[i][j][r] + bb);
        }
    }
}

// ---------------- K2: v[b][n][e] -> vt[b][e][n] ------------------------------
__global__ void v_transpose(const _Float16* __restrict__ v, _Float16* __restrict__ vt) {
    __shared__ alignas(16) _Float16 T[64][72];
    const int b = blockIdx.z;
    const int n0 = blockIdx.x * 64, e0 = blockIdx.y * 64;
    const int tid = threadIdx.x;
    #pragma unroll
    for (int i = 0; i < 2; ++i) {
        int c = tid + i * 256;
        int row = c >> 3, o = c & 7;
        int4 val = *(const int4*)(v + ((size_t)b * NSEQ + n0 + row) * 512 + e0 + o * 8);
        *(int4*)&T[row][o * 8] = val;
    }
    __syncthreads();
    #pragma unroll
    for (int i = 0; i < 2; ++i) {
        int c = tid + i * 256;
        int erow = c >> 3, o = c & 7;
        _Float16 tmp[8];
        #pragma unroll
        for (int j = 0; j < 8; ++j) tmp[j] = T[o * 8 + j][erow];
        *(int4*)(vt + (size_t)b * 512 * NSEQ + (size_t)(e0 + erow) * NSEQ + n0 + o * 8) =
            *(int4*)tmp;
    }
}

// ---------------- K3: flash attention (no scale) -----------------------------
// block = 64 q-rows (4 waves x 16), loop 64 K-tiles of 32 keys.
__global__ __launch_bounds__(256, 2) void attn(
        const _Float16* __restrict__ q, const _Float16* __restrict__ k,
        const _Float16* __restrict__ vt, float* __restrict__ out) {
    __shared__ alignas(16) char Ks[32 * 1024];          // [key][512 f16] swizzled
    __shared__ alignas(16) char Vs[512 * 64];           // [e][32 f16] swizzled
    __shared__ alignas(16) _Float16 Pl[4][16][40];      // per-wave P relayout
    const int tid = threadIdx.x, lane = tid & 63, wid = tid >> 6;
    const int lg = lane >> 4, lm = lane & 15;
    const int b  = blockIdx.y;
    const int n0 = blockIdx.x * 64;

    // Q fragments in registers: rows = n0 + wid*16 + lm
    const _Float16* qrow = q + ((size_t)(b * NSEQ + n0 + wid * 16 + lm)) * 512;
    half8 qf[16];
    #pragma unroll
    for (int es = 0; es < 16; ++es)
        qf[es] = *(const half8*)(qrow + es * 32 + lg * 8);

    f32x4 o[32] = {};
    float m_r[4], l_r[4];
    #pragma unroll
    for (int r = 0; r < 4; ++r) { m_r[r] = -__builtin_inff(); l_r[r] = 0.f; }

    const _Float16* kb  = k  + (size_t)b * NSEQ * 512;
    const _Float16* vtb = vt + (size_t)b * 512 * NSEQ;

    for (int t = 0; t < 64; ++t) {
        __syncthreads();
        // stage K tile: 32 rows x 1KB
        #pragma unroll
        for (int i = 0; i < 8; ++i) {
            int c = tid + i * 256;             // 2048 chunks
            int row = c >> 6, o16 = c & 63;
            int4 val = *(const int4*)(kb + (size_t)(t * 32 + row) * 512 + o16 * 8);
            *(int4*)(Ks + row * 1024 + ((o16 * 16) ^ ((row & 7) << 4))) = val;
        }
        // stage V tile: 512 rows(e) x 64B
        #pragma unroll
        for (int i = 0; i < 8; ++i) {
            int c = tid + i * 256;             // 2048 chunks
            int e = c >> 2, o16 = c & 3;
            int4 val = *(const int4*)(vtb + (size_t)e * NSEQ + t * 32 + o16 * 8);
            *(int4*)(Vs + e * 64 + ((o16 * 16) ^ ((e & 3) << 4))) = val;
        }
        __syncthreads();

        // QK^T: A=Q (rows), B=K^T; s0 = keys 0-15, s1 = keys 16-31
        f32x4 s0 = {}, s1 = {};
        #pragma unroll
        for (int es = 0; es < 16; ++es) {
            const int off = es * 64 + lg * 16;
            const int r0 = lm, r1 = lm + 16;
            half8 k0 = *(const half8*)(Ks + r0 * 1024 + (off ^ ((r0 & 7) << 4)));
            half8 k1 = *(const half8*)(Ks + r1 * 1024 + (off ^ ((r1 & 7) << 4)));
            s0 = __builtin_amdgcn_mfma_f32_16x16x32_f16(qf[es], k0, s0, 0, 0, 0);
            s1 = __builtin_amdgcn_mfma_f32_16x16x32_f16(qf[es], k1, s1, 0, 0, 0);
        }

        // online softmax per C-fragment row (row = lg*4 + r, col = key)
        float sc[4], p0[4], p1[4];
        #pragma unroll
        for (int r = 0; r < 4; ++r) {
            float tm = fmaxf(s0[r], s1[r]);
            #pragma unroll
            for (int d = 1; d < 16; d <<= 1) tm = fmaxf(tm, __shfl_xor(tm, d));
            float mn = fmaxf(m_r[r], tm);
            sc[r] = __expf(m_r[r] - mn);
            p0[r] = __expf(s0[r] - mn);
            p1[r] = __expf(s1[r] - mn);
            float rsum = p0[r] + p1[r];
            #pragma unroll
            for (int d = 1; d < 16; d <<= 1) rsum += __shfl_xor(rsum, d);
            l_r[r] = l_r[r] * sc[r] + rsum;
            m_r[r] = mn;
        }
        // rescale O
        #pragma unroll
        for (int eg = 0; eg < 32; ++eg)
            #pragma unroll
            for (int r = 0; r < 4; ++r) o[eg][r] *= sc[r];

        // P -> LDS (C-layout write), reread as A-fragment
        #pragma unroll
        for (int r = 0; r < 4; ++r) {
            Pl[wid][lg * 4 + r][lm]      = (_Float16)p0[r];
            Pl[wid][lg * 4 + r][lm + 16] = (_Float16)p1[r];
        }
        half8 pf = *(const half8*)&Pl[wid][lm][lg * 8];

        // PV: A=P (16x32), B=V (32 x 16 per e-group) from Vs[e][k]
        #pragma unroll
        for (int eg = 0; eg < 32; ++eg) {
            int e = eg * 16 + lm;
            half8 vf = *(const half8*)(Vs + e * 64 + ((lg * 16) ^ ((e & 3) << 4)));
            o[eg] = __builtin_amdgcn_mfma_f32_16x16x32_f16(pf, vf, o[eg], 0, 0, 0);
        }
    }

    // epilogue: normalize, store fp32. Output row = n0 + wid*16 + lg*4 + r, col = eg*16+lm
    float inv[4];
    #pragma unroll
    for (int r = 0; r < 4; ++r) inv[r] = 1.f / l_r[r];
    float* ob = out + ((size_t)(b * NSEQ + n0 + wid * 16 + lg * 4)) * 512;
    #pragma unroll
    for (int eg = 0; eg < 32; ++eg)
        #pragma unroll
        for (int r = 0; r < 4; ++r)
            ob[(size_t)r * 512 + eg * 16 + lm] = o[eg][r] * inv[r];
}

// ---------------- launcher ---------------------------------------------------
extern "C" void kernel_launch(void* const* d_in, const int* in_sizes, int n_in,
                              void* d_out, int out_size, void* d_ws, size_t ws_size,
                              hipStream_t stream) {
    const float* x  = (const float*)d_in[0];
    const float* Wq = (const float*)d_in[1];
    const float* bq = (const float*)d_in[2];
    const float* Wk = (const float*)d_in[3];
    const float* bk = (const float*)d_in[4];
    const float* Wv = (const float*)d_in[5];
    const float* bv = (const float*)d_in[6];
    float* out = (float*)d_out;
    char* ws = (char*)d_ws;

    _Float16* wt   = (_Float16*)(ws + WT_OFF);
    _Float16* qkv  = (_Float16*)(ws + QKV_OFF);
    _Float16* qbuf = qkv;
    _Float16* kbuf = qkv + (size_t)1 * MROWS * DDIM;
    _Float16* vbuf = qkv + (size_t)2 * MROWS * DDIM;
    _Float16* vt   = (_Float16*)(ws + VT_OFF);

    wt_prep<<<(1536 * 512) / 256, 256, 0, stream>>>(Wq, Wk, Wv, wt);
    qkv_gemm<<<dim3(MROWS / 64, 1536 / 64), 256, 0, stream>>>(x, wt, bq, bk, bv, qkv);
    v_transpose<<<dim3(NSEQ / 64, DDIM / 64, BATCH), 256, 0, stream>>>(vbuf, vt);
    attn<<<dim3(NSEQ / 64, BATCH), 256, 0, stream>>>(qbuf, kbuf, vt, out);
}

// Round 3
// 469.105 us; speedup vs baseline: 1.8835x; 1.8835x over previous
//
#include <hip/hip_runtime.h>

typedef _Float16 half8  __attribute__((ext_vector_type(8)));
typedef _Float16 half4_t __attribute__((ext_vector_type(4)));
typedef float    f32x4  __attribute__((ext_vector_type(4)));

static constexpr int BATCH = 16;
static constexpr int NSEQ  = 2048;
static constexpr int DDIM  = 512;
static constexpr int MROWS = BATCH * NSEQ;   // 32768

// workspace layout (bytes)
static constexpr size_t WT_OFF  = 0;                                      // 1.5MB
static constexpr size_t QKV_OFF = 2u * 1024 * 1024;                       // 96MB
static constexpr size_t VT_OFF  = QKV_OFF + (size_t)3 * MROWS * DDIM * 2; // 32MB (vt; also xh before v_transpose)

// async global->LDS, 16B per lane, dest = uniform base + lane*16
typedef const __attribute__((address_space(1))) void cg_void;
typedef __attribute__((address_space(3))) void lds_void;
__device__ __forceinline__ void gload_lds16(const void* g, void* l) {
    __builtin_amdgcn_global_load_lds((cg_void*)g, (lds_void*)l, 16, 0, 0);
}

// ---------------- K0a: x fp32 -> fp16 ---------------------------------------
__global__ void xconv(const float* __restrict__ x, _Float16* __restrict__ xh) {
    size_t base = ((size_t)blockIdx.x * 256 + threadIdx.x) * 8;
    float4 a = *(const float4*)(x + base);
    float4 b = *(const float4*)(x + base + 4);
    half8 h;
    h[0] = (_Float16)a.x; h[1] = (_Float16)a.y; h[2] = (_Float16)a.z; h[3] = (_Float16)a.w;
    h[4] = (_Float16)b.x; h[5] = (_Float16)b.y; h[6] = (_Float16)b.z; h[7] = (_Float16)b.w;
    *(half8*)(xh + base) = h;
}

// ---------------- K0b: weight fp32 -> fp16, transposed Wt[ng][e] ------------
__global__ void wt_prep(const float* __restrict__ Wq, const float* __restrict__ Wk,
                        const float* __restrict__ Wv, _Float16* __restrict__ wt) {
    int idx = blockIdx.x * 256 + threadIdx.x;   // 1536*512 total
    int ng  = idx >> 9;
    int e   = idx & 511;
    const float* W = (ng < 512) ? Wq : (ng < 1024 ? Wk : Wv);
    wt[idx] = (_Float16)W[e * 512 + (ng & 511)];
}

// ---------------- K1: fused QKV projection GEMM (m97-style 128x128) ---------
// C[32768 x 1536] = xh * W + bias, fp16 in/out, fp32 accum.
__global__ __launch_bounds__(256, 2) void qkv_gemm(
        const _Float16* __restrict__ xh, const _Float16* __restrict__ wt,
        const float* __restrict__ bq, const float* __restrict__ bk,
        const float* __restrict__ bv, _Float16* __restrict__ qkv) {
    __shared__ alignas(16) char Asw[128 * 128];   // 128 rows x 64 f16, linear dest
    __shared__ alignas(16) char Bsw[128 * 128];
    const int tid  = threadIdx.x;
    const int lane = tid & 63;
    const int wid  = tid >> 6;
    const int lg = lane >> 4, lm = lane & 15;
    const int wr = wid >> 1, wc = wid & 1;

    // XCD-aware swizzle (3072 % 8 == 0 -> simple bijection)
    const int id = blockIdx.x;
    const int wg = (id & 7) * 384 + (id >> 3);
    const int bm = wg & 255, bn = wg >> 8;
    const int m0 = bm * 128, n0 = bn * 128;
    const int proj = n0 >> 9;
    const float* bias = (proj == 0) ? bq : (proj == 1 ? bk : bv);

    f32x4 acc[4][4] = {};

    // per-lane staging geometry: issue (wid*4+i) covers 8 rows of 128B
    const int rloc = (lane >> 3);          // row within 8-row group
    const int p    = lane & 7;             // granule within row

    for (int kk = 0; kk < 512; kk += 64) {
        __syncthreads();
        #pragma unroll
        for (int i = 0; i < 4; ++i) {
            int g = wid * 4 + i;           // 16 groups of 8 rows
            int r = g * 8 + rloc;
            gload_lds16(xh + (size_t)(m0 + r) * 512 + kk + ((p ^ (r & 7)) * 8),
                        Asw + g * 1024);
            gload_lds16(wt + (size_t)(n0 + r) * 512 + kk + ((p ^ (r & 7)) * 8),
                        Bsw + g * 1024);
        }
        __syncthreads();
        #pragma unroll
        for (int es = 0; es < 2; ++es) {
            half8 a[4], b[4];
            #pragma unroll
            for (int i = 0; i < 4; ++i) {
                int row = wr * 64 + i * 16 + lm;
                a[i] = *(const half8*)(Asw + row * 128 + (((es * 4 + lg) ^ (row & 7)) * 16));
            }
            #pragma unroll
            for (int j = 0; j < 4; ++j) {
                int row = wc * 64 + j * 16 + lm;
                b[j] = *(const half8*)(Bsw + row * 128 + (((es * 4 + lg) ^ (row & 7)) * 16));
            }
            #pragma unroll
            for (int i = 0; i < 4; ++i)
                #pragma unroll
                for (int j = 0; j < 4; ++j)
                    acc[i][j] = __builtin_amdgcn_mfma_f32_16x16x32_f16(a[i], b[j], acc[i][j], 0, 0, 0);
        }
    }
    // epilogue: bias + fp16 store
    const size_t pb = (size_t)proj * MROWS * DDIM;
    #pragma unroll
    for (int i = 0; i < 4; ++i) {
        #pragma unroll
        for (int j = 0; j < 4; ++j) {
            int mg = m0 + wr * 64 + i * 16 + lg * 4;
            int c  = (n0 & 511) + wc * 64 + j * 16 + lm;
            float bb = bias[c];
            #pragma unroll
            for (int r = 0; r < 4; ++r)
                qkv[pb + (size_t)(mg + r) * DDIM + c] = (_Float16)(acc[i][j][r] + bb);
        }
    }
}

// ---------------- K2: v[b][n][e] -> vt[b][e][n] ------------------------------
__global__ void v_transpose(const _Float16* __restrict__ v, _Float16* __restrict__ vt) {
    __shared__ alignas(16) _Float16 T[64][72];
    const int b = blockIdx.z;
    const int n0 = blockIdx.x * 64, e0 = blockIdx.y * 64;
    const int tid = threadIdx.x;
    #pragma unroll
    for (int i = 0; i < 2; ++i) {
        int c = tid + i * 256;
        int row = c >> 3, o = c & 7;
        int4 val = *(const int4*)(v + ((size_t)b * NSEQ + n0 + row) * 512 + e0 + o * 8);
        *(int4*)&T[row][o * 8] = val;
    }
    __syncthreads();
    #pragma unroll
    for (int i = 0; i < 2; ++i) {
        int c = tid + i * 256;
        int erow = c >> 3, o = c & 7;
        _Float16 tmp[8];
        #pragma unroll
        for (int j = 0; j < 8; ++j) tmp[j] = T[o * 8 + j][erow];
        *(int4*)(vt + (size_t)b * 512 * NSEQ + (size_t)(e0 + erow) * NSEQ + n0 + o * 8) =
            *(int4*)tmp;
    }
}

// ---------------- K3: flash attention, 8 waves, dbuf global_load_lds ---------
// block = 128 q-rows (8 waves x 16), 64 K-tiles of 32 keys, 2-phase pipeline.
__global__ __launch_bounds__(512, 2) void attn(
        const _Float16* __restrict__ q, const _Float16* __restrict__ k,
        const _Float16* __restrict__ vt, float* __restrict__ out) {
    // [2][32KB] K (rows: key, swz p^(row&7)) + [2][32KB] V ([e][32key], swz p^((e>>1)&3)) + Pl
    __shared__ alignas(16) char smem[2 * 32768 + 2 * 32768 + 8 * 16 * 40 * 2];
    char* KsB = smem;
    char* VsB = smem + 65536;
    _Float16 (*Pl)[16][40] = (_Float16 (*)[16][40])(smem + 131072);

    const int tid = threadIdx.x, lane = tid & 63, wid = tid >> 6;   // wid 0..7
    const int lg = lane >> 4, lm = lane & 15;
    const int id = blockIdx.x;
    const int b  = id & 15;                 // XCD heuristic: batch = id%16 -> 2 batches/XCD
    const int n0 = (id >> 4) * 128;

    // Q fragments in registers: rows = n0 + wid*16 + lm
    const _Float16* qrow = q + ((size_t)(b * NSEQ + n0 + wid * 16 + lm)) * 512;
    half8 qf[16];
    #pragma unroll
    for (int es = 0; es < 16; ++es)
        qf[es] = *(const half8*)(qrow + es * 32 + lg * 8);

    f32x4 o[32] = {};
    float m_r[4], l_r[4];
    #pragma unroll
    for (int r = 0; r < 4; ++r) { m_r[r] = -__builtin_inff(); l_r[r] = 0.f; }

    const _Float16* kb  = k  + (size_t)b * NSEQ * 512;
    const _Float16* vtb = vt + (size_t)b * 512 * NSEQ;

    // staging offsets (elements). K issue i: row R=wid*4+i (1KB). V issue i: chunk C (16 e-rows).
    int koff[4], voff[4];
    #pragma unroll
    for (int i = 0; i < 4; ++i) {
        int R = wid * 4 + i;
        koff[i] = R * 512 + ((lane ^ (R & 7)) * 8);
        voff[i] = (R * 16 + (lane >> 2)) * NSEQ + (((lane & 3) ^ ((lane >> 3) & 3)) * 8);
    }

    // prologue: stage tile 0 -> buf 0
    #pragma unroll
    for (int i = 0; i < 4; ++i) {
        gload_lds16(kb + koff[i], KsB + (wid * 4 + i) * 1024);
        gload_lds16(vtb + voff[i], VsB + (wid * 4 + i) * 1024);
    }

    int buf = 0;
    for (int t = 0; t < 64; ++t) {
        __syncthreads();   // drains vmcnt: tile t resident in buf
        if (t < 63) {      // stage tile t+1 -> buf^1 (flies during compute)
            const _Float16* ks = kb + (size_t)(t + 1) * (32 * 512);
            const _Float16* vs = vtb + (size_t)(t + 1) * 32;
            const int nb = buf ^ 1;
            #pragma unroll
            for (int i = 0; i < 4; ++i) {
                gload_lds16(ks + koff[i], KsB + nb * 32768 + (wid * 4 + i) * 1024);
                gload_lds16(vs + voff[i], VsB + nb * 32768 + (wid * 4 + i) * 1024);
            }
        }
        const char* Ksb = KsB + buf * 32768;
        const char* Vsb = VsB + buf * 32768;

        // QK^T
        f32x4 s0 = {}, s1 = {};
        #pragma unroll
        for (int es = 0; es < 16; ++es) {
            const int off = es * 64 + lg * 16;
            half8 k0 = *(const half8*)(Ksb + lm * 1024 + (off ^ ((lm & 7) << 4)));
            half8 k1 = *(const half8*)(Ksb + (lm + 16) * 1024 + (off ^ ((lm & 7) << 4)));
            s0 = __builtin_amdgcn_mfma_f32_16x16x32_f16(qf[es], k0, s0, 0, 0, 0);
            s1 = __builtin_amdgcn_mfma_f32_16x16x32_f16(qf[es], k1, s1, 0, 0, 0);
        }

        // online softmax (row = q-row lg*4+r, cols = keys across lm)
        float sc[4], p0[4], p1[4];
        #pragma unroll
        for (int r = 0; r < 4; ++r) {
            float tm = fmaxf(s0[r], s1[r]);
            #pragma unroll
            for (int d = 1; d < 16; d <<= 1) tm = fmaxf(tm, __shfl_xor(tm, d));
            float mn = fmaxf(m_r[r], tm);
            sc[r] = __expf(m_r[r] - mn);
            p0[r] = __expf(s0[r] - mn);
            p1[r] = __expf(s1[r] - mn);
            float rsum = p0[r] + p1[r];
            #pragma unroll
            for (int d = 1; d < 16; d <<= 1) rsum += __shfl_xor(rsum, d);
            l_r[r] = l_r[r] * sc[r] + rsum;
            m_r[r] = mn;
        }
        #pragma unroll
        for (int eg = 0; eg < 32; ++eg)
            #pragma unroll
            for (int r = 0; r < 4; ++r) o[eg][r] *= sc[r];

        // P relayout via per-wave LDS (C-layout write, A-fragment read)
        #pragma unroll
        for (int r = 0; r < 4; ++r) {
            Pl[wid][lg * 4 + r][lm]      = (_Float16)p0[r];
            Pl[wid][lg * 4 + r][lm + 16] = (_Float16)p1[r];
        }
        half8 pf = *(const half8*)&Pl[wid][lm][lg * 8];

        // PV
        #pragma unroll
        for (int eg = 0; eg < 32; ++eg) {
            int e = eg * 16 + lm;
            half8 vf = *(const half8*)(Vsb + e * 64 + ((lg ^ ((lm >> 1) & 3)) << 4));
            o[eg] = __builtin_amdgcn_mfma_f32_16x16x32_f16(pf, vf, o[eg], 0, 0, 0);
        }
        buf ^= 1;
    }

    // epilogue
    float inv[4];
    #pragma unroll
    for (int r = 0; r < 4; ++r) inv[r] = 1.f / l_r[r];
    float* ob = out + ((size_t)(b * NSEQ + n0 + wid * 16 + lg * 4)) * 512;
    #pragma unroll
    for (int eg = 0; eg < 32; ++eg)
        #pragma unroll
        for (int r = 0; r < 4; ++r)
            ob[(size_t)r * 512 + eg * 16 + lm] = o[eg][r] * inv[r];
}

// ---------------- launcher ---------------------------------------------------
extern "C" void kernel_launch(void* const* d_in, const int* in_sizes, int n_in,
                              void* d_out, int out_size, void* d_ws, size_t ws_size,
                              hipStream_t stream) {
    const float* x  = (const float*)d_in[0];
    const float* Wq = (const float*)d_in[1];
    const float* bq = (const float*)d_in[2];
    const float* Wk = (const float*)d_in[3];
    const float* bk = (const float*)d_in[4];
    const float* Wv = (const float*)d_in[5];
    const float* bv = (const float*)d_in[6];
    float* out = (float*)d_out;
    char* ws = (char*)d_ws;

    _Float16* wt   = (_Float16*)(ws + WT_OFF);
    _Float16* qkv  = (_Float16*)(ws + QKV_OFF);
    _Float16* qbuf = qkv;
    _Float16* kbuf = qkv + (size_t)1 * MROWS * DDIM;
    _Float16* vbuf = qkv + (size_t)2 * MROWS * DDIM;
    _Float16* vt   = (_Float16*)(ws + VT_OFF);
    _Float16* xh   = (_Float16*)(ws + VT_OFF);   // aliased: xh dead before v_transpose writes vt

    xconv<<<8192, 256, 0, stream>>>(x, xh);
    wt_prep<<<(1536 * 512) / 256, 256, 0, stream>>>(Wq, Wk, Wv, wt);
    qkv_gemm<<<3072, 256, 0, stream>>>(xh, wt, bq, bk, bv, qkv);
    v_transpose<<<dim3(NSEQ / 64, DDIM / 64, BATCH), 256, 0, stream>>>(vbuf, vt);
    attn<<<256, 512, 0, stream>>>(qbuf, kbuf, vt, out);
}